// Round 17
// baseline (310.816 us; speedup 1.0000x reference)
//
#include <hip/hip_runtime.h>

#define NN 100000
#define EE 1000000
#define ET (EE + NN)
#define HC 128
#define NB 391           // ceil(NN/256)
#define AGG_BLOCKS 2048  // persistent blocks for k_agg
#define NGRP (NN / 4)    // 25000 node groups of 4
#define NTILE 6250       // NN/16 row-tiles
#define GEMM_BLKS 768    // gemm blocks inside k_gemmhist (then 256 hist blocks)

typedef __attribute__((ext_vector_type(8))) short short8;
typedef __attribute__((ext_vector_type(4))) float f32x4;
typedef __attribute__((ext_vector_type(2))) float f32x2;

// pack two floats to bf16x2 (RNE) in ONE instruction: a->low16, b->high16
__device__ __forceinline__ unsigned cvtpk(float a, float b) {
    unsigned r;
    asm("v_cvt_pk_bf16_f32 %0, %1, %2" : "=v"(r) : "v"(a), "v"(b));
    return r;
}

// ---- K1: fused  [blocks 0..767]: h = x@W via MFMA (+ attention dots)
//                 [blocks 768..1023]: degree histogram (independent, overlapped)
__global__ __launch_bounds__(256) void k_gemmhist(
    const float* __restrict__ x, const float* __restrict__ W,
    const float* __restrict__ atts, const float* __restrict__ attd,
    unsigned* __restrict__ hB, float2* __restrict__ asrc2, float2* __restrict__ adst2,
    const int* __restrict__ ei, int* __restrict__ hist)
{
    __shared__ uint4 wl[2048];   // 32 KB: B-fragments for all (ks, nt)

    if (blockIdx.x >= GEMM_BLKS) {
        // ---- histogram branch ----
        const int t0 = (blockIdx.x - GEMM_BLKS) * 256 + threadIdx.x;
        for (int t = t0; t < ET; t += 256 * 256) {
            int d = (t < EE) ? ei[EE + t] : (t - EE);
            atomicAdd(&hist[d], 1);
        }
        return;
    }

    // ---- gemm branch: pack W into B-fragment layout directly (L2-broadcast) ----
    for (int i = threadIdx.x; i < 2048; i += 256) {
        const int bid = i >> 6, l = i & 63;
        const int ks = bid >> 3, nt = bid & 7;
        const int n = nt * 16 + (l & 15);
        const int k0 = ks * 32 + (l >> 4) * 8;
        wl[i] = make_uint4(cvtpk(W[(k0 + 0) * HC + n], W[(k0 + 1) * HC + n]),
                           cvtpk(W[(k0 + 2) * HC + n], W[(k0 + 3) * HC + n]),
                           cvtpk(W[(k0 + 4) * HC + n], W[(k0 + 5) * HC + n]),
                           cvtpk(W[(k0 + 6) * HC + n], W[(k0 + 7) * HC + n]));
    }
    __syncthreads();

    const int wv = threadIdx.x >> 6, lane = threadIdx.x & 63;
    const int g = lane >> 4, c15 = lane & 15;

    float As[8], Ad[8];
    #pragma unroll
    for (int nt = 0; nt < 8; ++nt) {
        As[nt] = atts[nt * 16 + c15];
        Ad[nt] = attd[nt * 16 + c15];
    }

    for (int t = blockIdx.x * 4 + wv; t < NTILE; t += GEMM_BLKS * 4) {
        const int row0 = t * 16;
        union { unsigned u[4]; short8 v; } af[4];
        const float* xr = x + (size_t)(row0 + c15) * HC + g * 8;
        #pragma unroll
        for (int ks = 0; ks < 4; ++ks) {
            float4 lo = *(const float4*)(xr + ks * 32);
            float4 hi = *(const float4*)(xr + ks * 32 + 4);
            af[ks].u[0] = cvtpk(lo.x, lo.y);
            af[ks].u[1] = cvtpk(lo.z, lo.w);
            af[ks].u[2] = cvtpk(hi.x, hi.y);
            af[ks].u[3] = cvtpk(hi.z, hi.w);
        }
        f32x4 acc[8];
        #pragma unroll
        for (int nt = 0; nt < 8; ++nt) acc[nt] = (f32x4)(0.f);
        #pragma unroll
        for (int nt = 0; nt < 8; ++nt) {
            #pragma unroll
            for (int ks = 0; ks < 4; ++ks) {
                short8 bfr = *(const short8*)&wl[(ks * 8 + nt) * 64 + lane];
                acc[nt] = __builtin_amdgcn_mfma_f32_16x16x32_bf16(
                    af[ks].v, bfr, acc[nt], 0, 0, 0);
            }
        }
        #pragma unroll
        for (int r = 0; r < 4; ++r) {
            const int row = row0 + g * 4 + r;
            float ps = 0.f, pd = 0.f, qs = 0.f, qd = 0.f;
            #pragma unroll
            for (int nt = 0; nt < 4; ++nt) {
                float a = acc[nt][r], b = acc[nt + 4][r];
                hB[(size_t)row * 64 + nt * 16 + c15] = cvtpk(a, b);
                ps += a * As[nt];     qs += a * Ad[nt];
                pd += b * As[nt + 4]; qd += b * Ad[nt + 4];
            }
            for (int off = 8; off; off >>= 1) {
                ps += __shfl_xor(ps, off); pd += __shfl_xor(pd, off);
                qs += __shfl_xor(qs, off); qd += __shfl_xor(qd, off);
            }
            if (c15 == 0) {
                asrc2[row] = make_float2(ps, pd);
                adst2[row] = make_float2(qs, qd);
            }
        }
    }
}

__device__ __forceinline__ void edge_sd(const int* __restrict__ ei, int t, int& s, int& d) {
    if (t < EE) { s = ei[t]; d = ei[EE + t]; }
    else        { s = t - EE; d = t - EE; }           // self-loops appended
}

// ---- CSR scan: per-256-block sums ----
__global__ __launch_bounds__(256) void k_scan1(const int* __restrict__ hist,
                                               int* __restrict__ part)
{
    __shared__ int ls[256];
    int i = blockIdx.x * 256 + threadIdx.x;
    ls[threadIdx.x] = (i < NN) ? hist[i] : 0;
    __syncthreads();
    for (int off = 128; off; off >>= 1) {
        if (threadIdx.x < off) ls[threadIdx.x] += ls[threadIdx.x + off];
        __syncthreads();
    }
    if (!threadIdx.x) part[blockIdx.x] = ls[0];
}

// ---- scan3 (with fused scan-of-partials): row_ptr = exclusive scan of hist ----
__global__ __launch_bounds__(256) void k_scan3(const int* __restrict__ hist,
                                               const int* __restrict__ part,
                                               int* __restrict__ row_ptr)
{
    __shared__ int ls[256];
    __shared__ int bofs[NB];
    const int tid = threadIdx.x;
    if (tid < 64) {                      // wave 0: exclusive scan of 391 partials
        int carry = 0;
        for (int c = 0; c < NB; c += 64) {
            const int idx = c + tid;
            int v = (idx < NB) ? part[idx] : 0;
            const int orig = v;
            for (int o = 1; o < 64; o <<= 1) {
                int u = __shfl_up(v, o);
                if (tid >= o) v += u;
            }
            if (idx < NB) bofs[idx] = carry + v - orig;
            carry += __shfl(v, 63);
        }
    }
    int i = blockIdx.x * 256 + tid;
    int v = (i < NN) ? hist[i] : 0;
    ls[tid] = v;
    __syncthreads();
    for (int off = 1; off < 256; off <<= 1) {
        int t = (tid >= off) ? ls[tid - off] : 0;
        __syncthreads();
        ls[tid] += t;
        __syncthreads();
    }
    if (i < NN) row_ptr[i] = bofs[blockIdx.x] + ls[tid] - v;  // exclusive
    if (i == 0) row_ptr[NN] = ET;
}

// bucket edges by dst; ONE scattered 8B write per edge: {src, p as bf16x2}
__global__ __launch_bounds__(256) void k_bucket(
    const int* __restrict__ ei, const float* __restrict__ asrc,
    const float* __restrict__ adst, const int* __restrict__ row_ptr,
    int* __restrict__ cursor, uint2* __restrict__ csr8)
{
    int t = blockIdx.x * 256 + threadIdx.x;
    if (t >= ET) return;
    int s, d; edge_sd(ei, t, s, d);
    float2 av = *(const float2*)&asrc[s * 2];
    float2 dv = *(const float2*)&adst[d * 2];
    float e0 = av.x + dv.x; e0 = e0 > 0.f ? e0 : 0.2f * e0;
    float e1 = av.y + dv.y; e1 = e1 > 0.f ? e1 : 0.2f * e1;
    int pos = row_ptr[d] + atomicAdd(&cursor[d], 1);
    csr8[pos] = make_uint2((unsigned)s, cvtpk(__expf(e0), __expf(e1)));
}

// 8 dwordx2 gathers (= 16 edges, 2 edges/load) issued + drained in ONE asm
// block; nothing (spill/copy/compiler-wait) can land between issue and drain.
__device__ __forceinline__ void gather8x2(const unsigned* base, const unsigned* off,
                                          unsigned long long* w) {
    asm volatile(
        "global_load_dwordx2 %0, %8,  %16\n\t"
        "global_load_dwordx2 %1, %9,  %16\n\t"
        "global_load_dwordx2 %2, %10, %16\n\t"
        "global_load_dwordx2 %3, %11, %16\n\t"
        "global_load_dwordx2 %4, %12, %16\n\t"
        "global_load_dwordx2 %5, %13, %16\n\t"
        "global_load_dwordx2 %6, %14, %16\n\t"
        "global_load_dwordx2 %7, %15, %16\n\t"
        "s_waitcnt vmcnt(0)"
        : "=&v"(w[0]), "=&v"(w[1]), "=&v"(w[2]), "=&v"(w[3]),
          "=&v"(w[4]), "=&v"(w[5]), "=&v"(w[6]), "=&v"(w[7])
        : "v"(off[0]), "v"(off[1]), "v"(off[2]), "v"(off[3]),
          "v"(off[4]), "v"(off[5]), "v"(off[6]), "v"(off[7]),
          "s"(base)
        : "memory");
}

// ---- K-agg: 8B csr entries, 16 edges in flight; streaming data marked
// non-temporal so the 4MB/XCD L2 keeps hB lines instead (hB = the only
// reused data; csr8/out/bpart are touch-once).
__global__ __launch_bounds__(256) void k_agg(
    const int* __restrict__ row_ptr, const uint2* __restrict__ csr8,
    const unsigned* __restrict__ hB, const float* __restrict__ bias,
    float* __restrict__ out, float* __restrict__ bpart)
{
    __shared__ float lsum[HC], lsq[HC];
    __shared__ int    lidx[4][64];
    __shared__ float2 lp[4][64];
    const int tid = threadIdx.x;
    if (tid < HC) { lsum[tid] = 0.f; lsq[tid] = 0.f; }
    __syncthreads();

    const int wv = tid >> 6, lane = tid & 63;
    const int half = lane >> 5, m = lane & 31;
    const float bA0 = bias[2*m],      bB0 = bias[2*m + 1];
    const float bA1 = bias[2*m + 64], bB1 = bias[2*m + 65];

    for (int g = blockIdx.x; g < NGRP; g += AGG_BLOCKS) {
        const int node = g * 4 + wv;
        const int beg = row_ptr[node], end = row_ptr[node + 1];  // end > beg

        float s0 = 0.f, s1 = 0.f;
        float a0 = 0.f, a1 = 0.f, b0 = 0.f, b1 = 0.f;  // ch 2m, 2m+64, 2m+1, 2m+65

        for (int base = beg; base < end; base += 64) {
            const int cnt = min(64, end - base);   // >= 1
            if (lane < cnt) {
                // read-once stream: non-temporal (don't evict hB from L2)
                unsigned long long ev = __builtin_nontemporal_load(
                    (const unsigned long long*)(csr8 + base + lane));
                unsigned ex = (unsigned)ev, ey = (unsigned)(ev >> 32);
                float2 pv = make_float2(__uint_as_float(ey << 16),
                                        __uint_as_float(ey & 0xffff0000u));
                lidx[wv][lane] = (int)ex;
                lp[wv][lane] = pv;
                s0 += pv.x; s1 += pv.y;
            }
            for (int j0 = 0; j0 < cnt; j0 += 16) {
                unsigned off[8]; unsigned long long w[8];
                float px[8], py[8];
                #pragma unroll
                for (int u = 0; u < 8; ++u) {
                    int j  = j0 + 2 * u + half;
                    int jc = j < cnt ? j : cnt - 1;     // clamp (wave-uniform)
                    int s  = lidx[wv][jc];
                    float2 pv = lp[wv][jc];
                    px[u] = j < cnt ? pv.x : 0.f;       // zero pad weight
                    py[u] = j < cnt ? pv.y : 0.f;
                    off[u] = ((unsigned)s * 64u + (unsigned)m * 2u) * 4u;
                }
                gather8x2(hB, off, w);
                #pragma unroll
                for (int u = 0; u < 8; ++u) {
                    unsigned wlo = (unsigned)w[u];           // dword 2m
                    unsigned whi = (unsigned)(w[u] >> 32);   // dword 2m+1
                    a0 = fmaf(px[u], __uint_as_float(wlo << 16),          a0);
                    a1 = fmaf(py[u], __uint_as_float(wlo & 0xffff0000u),  a1);
                    b0 = fmaf(px[u], __uint_as_float(whi << 16),          b0);
                    b1 = fmaf(py[u], __uint_as_float(whi & 0xffff0000u),  b1);
                }
            }
        }

        // combine edge-halves, then full reduce of p-sums
        a0 += __shfl_xor(a0, 32); a1 += __shfl_xor(a1, 32);
        b0 += __shfl_xor(b0, 32); b1 += __shfl_xor(b1, 32);
        for (int o = 32; o; o >>= 1) {
            s0 += __shfl_xor(s0, o);
            s1 += __shfl_xor(s1, o);
        }
        const float i0 = 1.f / s0, i1 = 1.f / s1;

        if (half == 0) {
            float vA0 = a0 * i0 + bA0; vA0 = vA0 > 0.f ? vA0 : 0.f;  // ch 2m
            float vB0 = b0 * i0 + bB0; vB0 = vB0 > 0.f ? vB0 : 0.f;  // ch 2m+1
            float vA1 = a1 * i1 + bA1; vA1 = vA1 > 0.f ? vA1 : 0.f;  // ch 2m+64
            float vB1 = b1 * i1 + bB1; vB1 = vB1 > 0.f ? vB1 : 0.f;  // ch 2m+65
            // write-once stream: non-temporal
            f32x2 o0 = {vA0, vB0}, o1 = {vA1, vB1};
            __builtin_nontemporal_store(o0, (f32x2*)&out[(size_t)node * HC + 2*m]);
            __builtin_nontemporal_store(o1, (f32x2*)&out[(size_t)node * HC + 64 + 2*m]);
            atomicAdd(&lsum[2*m],      vA0); atomicAdd(&lsq[2*m],      vA0 * vA0);
            atomicAdd(&lsum[2*m + 1],  vB0); atomicAdd(&lsq[2*m + 1],  vB0 * vB0);
            atomicAdd(&lsum[2*m + 64], vA1); atomicAdd(&lsq[2*m + 64], vA1 * vA1);
            atomicAdd(&lsum[2*m + 65], vB1); atomicAdd(&lsq[2*m + 65], vB1 * vB1);
        }
    }

    __syncthreads();
    float pv = tid < HC ? lsum[tid] : lsq[tid - HC];
    __builtin_nontemporal_store(pv, &bpart[(size_t)blockIdx.x * 256 + tid]);
}

// ---- reduce bpart[2048][256] -> p2[16][256] (atomic-free) ----
__global__ __launch_bounds__(256) void k_red(const float* __restrict__ bpart,
                                             float* __restrict__ p2)
{
    const int tid = threadIdx.x;
    float acc = 0.f;
    const int r0 = blockIdx.x * (AGG_BLOCKS / 16);
    #pragma unroll 4
    for (int r = 0; r < AGG_BLOCKS / 16; ++r)
        acc += bpart[(size_t)(r0 + r) * 256 + tid];
    p2[blockIdx.x * 256 + tid] = acc;
}

// ---- affine apply (BN params derived in-block from p2) ----
__global__ __launch_bounds__(256) void k_apply(
    const float* __restrict__ p2, const float* __restrict__ gamma,
    const float* __restrict__ beta, float* __restrict__ out)
{
    __shared__ float scsh[256];
    const int tid = threadIdx.x;
    if (tid < HC) {
        float sum = 0.f, sq = 0.f;
        #pragma unroll
        for (int i = 0; i < 16; ++i) {
            sum += p2[i * 256 + tid];
            sq  += p2[i * 256 + tid + 128];
        }
        float mean = sum * (1.f / NN);
        float var  = sq * (1.f / NN) - mean * mean;
        float sc   = gamma[tid] * rsqrtf(var + 1e-5f);
        scsh[tid]       = sc;
        scsh[128 + tid] = beta[tid] - mean * sc;
    }
    __syncthreads();
    for (size_t i = (size_t)blockIdx.x * 256 + tid; i < (size_t)NN * HC / 4;
         i += (size_t)gridDim.x * 256) {
        float4 v = ((float4*)out)[i];
        int c = (int)((i * 4) & (HC - 1));
        v.x = v.x * scsh[c]     + scsh[128 + c];
        v.y = v.y * scsh[c + 1] + scsh[128 + c + 1];
        v.z = v.z * scsh[c + 2] + scsh[128 + c + 2];
        v.w = v.w * scsh[c + 3] + scsh[128 + c + 3];
        ((float4*)out)[i] = v;
    }
}

extern "C" void kernel_launch(void* const* d_in, const int* in_sizes, int n_in,
                              void* d_out, int out_size, void* d_ws, size_t ws_size,
                              hipStream_t stream) {
    const float* x     = (const float*)d_in[0];
    const int*   ei    = (const int*)  d_in[1];
    const float* W     = (const float*)d_in[2];
    const float* atts  = (const float*)d_in[3];
    const float* attd  = (const float*)d_in[4];
    const float* bias  = (const float*)d_in[5];
    const float* gamma = (const float*)d_in[6];
    const float* beta  = (const float*)d_in[7];
    float* out = (float*)d_out;
    float* ws  = (float*)d_ws;

    // ws layout (float-sized slots), ~40 MB total
    unsigned* hB     = (unsigned*)ws;             //  6,400,000
    float*    asrc   = ws + 6400000;              //    200,000
    float*    adst   = ws + 6600000;              //    200,000
    int*      hist   = (int*)(ws + 6800000);      //    100,000  \  zeroed
    int*      cursor = (int*)(ws + 6900000);      //    100,000  /  region
    int*      row_ptr= (int*)(ws + 7000512);      //    100,001
    int*      part   = (int*)(ws + 7100513);      //        512
    uint2*    csr8   = (uint2*)(ws + 7101026);    //  2,200,000 floats (8B aligned)
    float*    bpart  = ws + 9301026;              //    524,288 (2048*256)
    float*    p2     = ws + 9825314;              //      4,096 (16*256)

    hipMemsetAsync(hist, 0, (size_t)200000 * sizeof(int), stream);

    k_gemmhist<<<1024, 256, 0, stream>>>(x, W, atts, attd, hB,
                                         (float2*)asrc, (float2*)adst, ei, hist);
    k_scan1   <<<NB, 256, 0, stream>>>(hist, part);
    k_scan3   <<<NB, 256, 0, stream>>>(hist, part, row_ptr);
    k_bucket  <<<(ET + 255) / 256, 256, 0, stream>>>(ei, asrc, adst, row_ptr,
                                                     cursor, csr8);
    k_agg     <<<AGG_BLOCKS, 256, 0, stream>>>(row_ptr, csr8, hB, bias,
                                               out, bpart);
    k_red     <<<16, 256, 0, stream>>>(bpart, p2);
    k_apply   <<<2048, 256, 0, stream>>>(p2, gamma, beta, out);
}

// Round 18
// 309.483 us; speedup vs baseline: 1.0043x; 1.0043x over previous
//
#include <hip/hip_runtime.h>

#define NN 100000
#define EE 1000000
#define ET (EE + NN)
#define HC 128
#define NB 391           // ceil(NN/256)
#define AGG_BLOCKS 2048  // persistent blocks for k_agg
#define NGRP (NN / 4)    // 25000 node groups of 4
#define NTILE 6250       // NN/16 row-tiles
#define GEMM_BLKS 768    // gemm blocks inside k_gemmhist (then 256 hist blocks)

typedef __attribute__((ext_vector_type(8))) short short8;
typedef __attribute__((ext_vector_type(4))) float f32x4;
typedef __attribute__((ext_vector_type(2))) float f32x2;

// pack two floats to bf16x2 (RNE) in ONE instruction: a->low16, b->high16
__device__ __forceinline__ unsigned cvtpk(float a, float b) {
    unsigned r;
    asm("v_cvt_pk_bf16_f32 %0, %1, %2" : "=v"(r) : "v"(a), "v"(b));
    return r;
}

// ---- K1: fused  [blocks 0..767]: h = x@W via MFMA (+ attention dots)
//                 [blocks 768..1023]: degree histogram (independent, overlapped)
__global__ __launch_bounds__(256) void k_gemmhist(
    const float* __restrict__ x, const float* __restrict__ W,
    const float* __restrict__ atts, const float* __restrict__ attd,
    unsigned* __restrict__ hB, float2* __restrict__ asrc2, float2* __restrict__ adst2,
    const int* __restrict__ ei, int* __restrict__ hist)
{
    __shared__ uint4 wl[2048];   // 32 KB: B-fragments for all (ks, nt)

    if (blockIdx.x >= GEMM_BLKS) {
        // ---- histogram branch ----
        const int t0 = (blockIdx.x - GEMM_BLKS) * 256 + threadIdx.x;
        for (int t = t0; t < ET; t += 256 * 256) {
            int d = (t < EE) ? ei[EE + t] : (t - EE);
            atomicAdd(&hist[d], 1);
        }
        return;
    }

    // ---- gemm branch: pack W into B-fragment layout directly (L2-broadcast) ----
    for (int i = threadIdx.x; i < 2048; i += 256) {
        const int bid = i >> 6, l = i & 63;
        const int ks = bid >> 3, nt = bid & 7;
        const int n = nt * 16 + (l & 15);
        const int k0 = ks * 32 + (l >> 4) * 8;
        wl[i] = make_uint4(cvtpk(W[(k0 + 0) * HC + n], W[(k0 + 1) * HC + n]),
                           cvtpk(W[(k0 + 2) * HC + n], W[(k0 + 3) * HC + n]),
                           cvtpk(W[(k0 + 4) * HC + n], W[(k0 + 5) * HC + n]),
                           cvtpk(W[(k0 + 6) * HC + n], W[(k0 + 7) * HC + n]));
    }
    __syncthreads();

    const int wv = threadIdx.x >> 6, lane = threadIdx.x & 63;
    const int g = lane >> 4, c15 = lane & 15;

    float As[8], Ad[8];
    #pragma unroll
    for (int nt = 0; nt < 8; ++nt) {
        As[nt] = atts[nt * 16 + c15];
        Ad[nt] = attd[nt * 16 + c15];
    }

    for (int t = blockIdx.x * 4 + wv; t < NTILE; t += GEMM_BLKS * 4) {
        const int row0 = t * 16;
        union { unsigned u[4]; short8 v; } af[4];
        const float* xr = x + (size_t)(row0 + c15) * HC + g * 8;
        #pragma unroll
        for (int ks = 0; ks < 4; ++ks) {
            float4 lo = *(const float4*)(xr + ks * 32);
            float4 hi = *(const float4*)(xr + ks * 32 + 4);
            af[ks].u[0] = cvtpk(lo.x, lo.y);
            af[ks].u[1] = cvtpk(lo.z, lo.w);
            af[ks].u[2] = cvtpk(hi.x, hi.y);
            af[ks].u[3] = cvtpk(hi.z, hi.w);
        }
        f32x4 acc[8];
        #pragma unroll
        for (int nt = 0; nt < 8; ++nt) acc[nt] = (f32x4)(0.f);
        #pragma unroll
        for (int nt = 0; nt < 8; ++nt) {
            #pragma unroll
            for (int ks = 0; ks < 4; ++ks) {
                short8 bfr = *(const short8*)&wl[(ks * 8 + nt) * 64 + lane];
                acc[nt] = __builtin_amdgcn_mfma_f32_16x16x32_bf16(
                    af[ks].v, bfr, acc[nt], 0, 0, 0);
            }
        }
        #pragma unroll
        for (int r = 0; r < 4; ++r) {
            const int row = row0 + g * 4 + r;
            float ps = 0.f, pd = 0.f, qs = 0.f, qd = 0.f;
            #pragma unroll
            for (int nt = 0; nt < 4; ++nt) {
                float a = acc[nt][r], b = acc[nt + 4][r];
                hB[(size_t)row * 64 + nt * 16 + c15] = cvtpk(a, b);
                ps += a * As[nt];     qs += a * Ad[nt];
                pd += b * As[nt + 4]; qd += b * Ad[nt + 4];
            }
            for (int off = 8; off; off >>= 1) {
                ps += __shfl_xor(ps, off); pd += __shfl_xor(pd, off);
                qs += __shfl_xor(qs, off); qd += __shfl_xor(qd, off);
            }
            if (c15 == 0) {
                asrc2[row] = make_float2(ps, pd);
                adst2[row] = make_float2(qs, qd);
            }
        }
    }
}

__device__ __forceinline__ void edge_sd(const int* __restrict__ ei, int t, int& s, int& d) {
    if (t < EE) { s = ei[t]; d = ei[EE + t]; }
    else        { s = t - EE; d = t - EE; }           // self-loops appended
}

// ---- CSR scan: per-256-block sums ----
__global__ __launch_bounds__(256) void k_scan1(const int* __restrict__ hist,
                                               int* __restrict__ part)
{
    __shared__ int ls[256];
    int i = blockIdx.x * 256 + threadIdx.x;
    ls[threadIdx.x] = (i < NN) ? hist[i] : 0;
    __syncthreads();
    for (int off = 128; off; off >>= 1) {
        if (threadIdx.x < off) ls[threadIdx.x] += ls[threadIdx.x + off];
        __syncthreads();
    }
    if (!threadIdx.x) part[blockIdx.x] = ls[0];
}

// ---- scan3 (with fused scan-of-partials): row_ptr = exclusive scan of hist ----
__global__ __launch_bounds__(256) void k_scan3(const int* __restrict__ hist,
                                               const int* __restrict__ part,
                                               int* __restrict__ row_ptr)
{
    __shared__ int ls[256];
    __shared__ int bofs[NB];
    const int tid = threadIdx.x;
    if (tid < 64) {                      // wave 0: exclusive scan of 391 partials
        int carry = 0;
        for (int c = 0; c < NB; c += 64) {
            const int idx = c + tid;
            int v = (idx < NB) ? part[idx] : 0;
            const int orig = v;
            for (int o = 1; o < 64; o <<= 1) {
                int u = __shfl_up(v, o);
                if (tid >= o) v += u;
            }
            if (idx < NB) bofs[idx] = carry + v - orig;
            carry += __shfl(v, 63);
        }
    }
    int i = blockIdx.x * 256 + tid;
    int v = (i < NN) ? hist[i] : 0;
    ls[tid] = v;
    __syncthreads();
    for (int off = 1; off < 256; off <<= 1) {
        int t = (tid >= off) ? ls[tid - off] : 0;
        __syncthreads();
        ls[tid] += t;
        __syncthreads();
    }
    if (i < NN) row_ptr[i] = bofs[blockIdx.x] + ls[tid] - v;  // exclusive
    if (i == 0) row_ptr[NN] = ET;
}

// bucket edges by dst; ONE scattered 8B write per edge: {src, p as bf16x2}
__global__ __launch_bounds__(256) void k_bucket(
    const int* __restrict__ ei, const float* __restrict__ asrc,
    const float* __restrict__ adst, const int* __restrict__ row_ptr,
    int* __restrict__ cursor, uint2* __restrict__ csr8)
{
    int t = blockIdx.x * 256 + threadIdx.x;
    if (t >= ET) return;
    int s, d; edge_sd(ei, t, s, d);
    float2 av = *(const float2*)&asrc[s * 2];
    float2 dv = *(const float2*)&adst[d * 2];
    float e0 = av.x + dv.x; e0 = e0 > 0.f ? e0 : 0.2f * e0;
    float e1 = av.y + dv.y; e1 = e1 > 0.f ? e1 : 0.2f * e1;
    int pos = row_ptr[d] + atomicAdd(&cursor[d], 1);
    csr8[pos] = make_uint2((unsigned)s, cvtpk(__expf(e0), __expf(e1)));
}

// 8 dwordx2 gathers (= 16 edges, 2 edges/load) issued + drained in ONE asm
// block; nothing (spill/copy/compiler-wait) can land between issue and drain.
__device__ __forceinline__ void gather8x2(const unsigned* base, const unsigned* off,
                                          unsigned long long* w) {
    asm volatile(
        "global_load_dwordx2 %0, %8,  %16\n\t"
        "global_load_dwordx2 %1, %9,  %16\n\t"
        "global_load_dwordx2 %2, %10, %16\n\t"
        "global_load_dwordx2 %3, %11, %16\n\t"
        "global_load_dwordx2 %4, %12, %16\n\t"
        "global_load_dwordx2 %5, %13, %16\n\t"
        "global_load_dwordx2 %6, %14, %16\n\t"
        "global_load_dwordx2 %7, %15, %16\n\t"
        "s_waitcnt vmcnt(0)"
        : "=&v"(w[0]), "=&v"(w[1]), "=&v"(w[2]), "=&v"(w[3]),
          "=&v"(w[4]), "=&v"(w[5]), "=&v"(w[6]), "=&v"(w[7])
        : "v"(off[0]), "v"(off[1]), "v"(off[2]), "v"(off[3]),
          "v"(off[4]), "v"(off[5]), "v"(off[6]), "v"(off[7]),
          "s"(base)
        : "memory");
}

// ---- K-agg: 8B csr entries, 16 edges in flight; streaming data marked
// non-temporal so the 4MB/XCD L2 keeps hB lines instead (hB = the only
// reused data; csr8/out/bpart are touch-once).
__global__ __launch_bounds__(256) void k_agg(
    const int* __restrict__ row_ptr, const uint2* __restrict__ csr8,
    const unsigned* __restrict__ hB, const float* __restrict__ bias,
    float* __restrict__ out, float* __restrict__ bpart)
{
    __shared__ float lsum[HC], lsq[HC];
    __shared__ int    lidx[4][64];
    __shared__ float2 lp[4][64];
    const int tid = threadIdx.x;
    if (tid < HC) { lsum[tid] = 0.f; lsq[tid] = 0.f; }
    __syncthreads();

    const int wv = tid >> 6, lane = tid & 63;
    const int half = lane >> 5, m = lane & 31;
    const float bA0 = bias[2*m],      bB0 = bias[2*m + 1];
    const float bA1 = bias[2*m + 64], bB1 = bias[2*m + 65];

    for (int g = blockIdx.x; g < NGRP; g += AGG_BLOCKS) {
        const int node = g * 4 + wv;
        const int beg = row_ptr[node], end = row_ptr[node + 1];  // end > beg

        float s0 = 0.f, s1 = 0.f;
        float a0 = 0.f, a1 = 0.f, b0 = 0.f, b1 = 0.f;  // ch 2m, 2m+64, 2m+1, 2m+65

        for (int base = beg; base < end; base += 64) {
            const int cnt = min(64, end - base);   // >= 1
            if (lane < cnt) {
                // read-once stream: non-temporal (don't evict hB from L2)
                unsigned long long ev = __builtin_nontemporal_load(
                    (const unsigned long long*)(csr8 + base + lane));
                unsigned ex = (unsigned)ev, ey = (unsigned)(ev >> 32);
                float2 pv = make_float2(__uint_as_float(ey << 16),
                                        __uint_as_float(ey & 0xffff0000u));
                lidx[wv][lane] = (int)ex;
                lp[wv][lane] = pv;
                s0 += pv.x; s1 += pv.y;
            }
            for (int j0 = 0; j0 < cnt; j0 += 16) {
                unsigned off[8]; unsigned long long w[8];
                float px[8], py[8];
                #pragma unroll
                for (int u = 0; u < 8; ++u) {
                    int j  = j0 + 2 * u + half;
                    int jc = j < cnt ? j : cnt - 1;     // clamp (wave-uniform)
                    int s  = lidx[wv][jc];
                    float2 pv = lp[wv][jc];
                    px[u] = j < cnt ? pv.x : 0.f;       // zero pad weight
                    py[u] = j < cnt ? pv.y : 0.f;
                    off[u] = ((unsigned)s * 64u + (unsigned)m * 2u) * 4u;
                }
                gather8x2(hB, off, w);
                #pragma unroll
                for (int u = 0; u < 8; ++u) {
                    unsigned wlo = (unsigned)w[u];           // dword 2m
                    unsigned whi = (unsigned)(w[u] >> 32);   // dword 2m+1
                    a0 = fmaf(px[u], __uint_as_float(wlo << 16),          a0);
                    a1 = fmaf(py[u], __uint_as_float(wlo & 0xffff0000u),  a1);
                    b0 = fmaf(px[u], __uint_as_float(whi << 16),          b0);
                    b1 = fmaf(py[u], __uint_as_float(whi & 0xffff0000u),  b1);
                }
            }
        }

        // combine edge-halves, then full reduce of p-sums
        a0 += __shfl_xor(a0, 32); a1 += __shfl_xor(a1, 32);
        b0 += __shfl_xor(b0, 32); b1 += __shfl_xor(b1, 32);
        for (int o = 32; o; o >>= 1) {
            s0 += __shfl_xor(s0, o);
            s1 += __shfl_xor(s1, o);
        }
        const float i0 = 1.f / s0, i1 = 1.f / s1;

        if (half == 0) {
            float vA0 = a0 * i0 + bA0; vA0 = vA0 > 0.f ? vA0 : 0.f;  // ch 2m
            float vB0 = b0 * i0 + bB0; vB0 = vB0 > 0.f ? vB0 : 0.f;  // ch 2m+1
            float vA1 = a1 * i1 + bA1; vA1 = vA1 > 0.f ? vA1 : 0.f;  // ch 2m+64
            float vB1 = b1 * i1 + bB1; vB1 = vB1 > 0.f ? vB1 : 0.f;  // ch 2m+65
            // write-once stream: non-temporal
            f32x2 o0 = {vA0, vB0}, o1 = {vA1, vB1};
            __builtin_nontemporal_store(o0, (f32x2*)&out[(size_t)node * HC + 2*m]);
            __builtin_nontemporal_store(o1, (f32x2*)&out[(size_t)node * HC + 64 + 2*m]);
            atomicAdd(&lsum[2*m],      vA0); atomicAdd(&lsq[2*m],      vA0 * vA0);
            atomicAdd(&lsum[2*m + 1],  vB0); atomicAdd(&lsq[2*m + 1],  vB0 * vB0);
            atomicAdd(&lsum[2*m + 64], vA1); atomicAdd(&lsq[2*m + 64], vA1 * vA1);
            atomicAdd(&lsum[2*m + 65], vB1); atomicAdd(&lsq[2*m + 65], vB1 * vB1);
        }
    }

    __syncthreads();
    float pv = tid < HC ? lsum[tid] : lsq[tid - HC];
    __builtin_nontemporal_store(pv, &bpart[(size_t)blockIdx.x * 256 + tid]);
}

// ---- reduce bpart[2048][256] -> p2[16][256] (atomic-free) ----
__global__ __launch_bounds__(256) void k_red(const float* __restrict__ bpart,
                                             float* __restrict__ p2)
{
    const int tid = threadIdx.x;
    float acc = 0.f;
    const int r0 = blockIdx.x * (AGG_BLOCKS / 16);
    #pragma unroll 4
    for (int r = 0; r < AGG_BLOCKS / 16; ++r)
        acc += bpart[(size_t)(r0 + r) * 256 + tid];
    p2[blockIdx.x * 256 + tid] = acc;
}

// ---- affine apply (BN params derived in-block from p2) ----
__global__ __launch_bounds__(256) void k_apply(
    const float* __restrict__ p2, const float* __restrict__ gamma,
    const float* __restrict__ beta, float* __restrict__ out)
{
    __shared__ float scsh[256];
    const int tid = threadIdx.x;
    if (tid < HC) {
        float sum = 0.f, sq = 0.f;
        #pragma unroll
        for (int i = 0; i < 16; ++i) {
            sum += p2[i * 256 + tid];
            sq  += p2[i * 256 + tid + 128];
        }
        float mean = sum * (1.f / NN);
        float var  = sq * (1.f / NN) - mean * mean;
        float sc   = gamma[tid] * rsqrtf(var + 1e-5f);
        scsh[tid]       = sc;
        scsh[128 + tid] = beta[tid] - mean * sc;
    }
    __syncthreads();
    for (size_t i = (size_t)blockIdx.x * 256 + tid; i < (size_t)NN * HC / 4;
         i += (size_t)gridDim.x * 256) {
        float4 v = ((float4*)out)[i];
        int c = (int)((i * 4) & (HC - 1));
        v.x = v.x * scsh[c]     + scsh[128 + c];
        v.y = v.y * scsh[c + 1] + scsh[128 + c + 1];
        v.z = v.z * scsh[c + 2] + scsh[128 + c + 2];
        v.w = v.w * scsh[c + 3] + scsh[128 + c + 3];
        ((float4*)out)[i] = v;
    }
}

extern "C" void kernel_launch(void* const* d_in, const int* in_sizes, int n_in,
                              void* d_out, int out_size, void* d_ws, size_t ws_size,
                              hipStream_t stream) {
    const float* x     = (const float*)d_in[0];
    const int*   ei    = (const int*)  d_in[1];
    const float* W     = (const float*)d_in[2];
    const float* atts  = (const float*)d_in[3];
    const float* attd  = (const float*)d_in[4];
    const float* bias  = (const float*)d_in[5];
    const float* gamma = (const float*)d_in[6];
    const float* beta  = (const float*)d_in[7];
    float* out = (float*)d_out;
    float* ws  = (float*)d_ws;

    // ws layout (float-sized slots), ~40 MB total
    unsigned* hB     = (unsigned*)ws;             //  6,400,000
    float*    asrc   = ws + 6400000;              //    200,000
    float*    adst   = ws + 6600000;              //    200,000
    int*      hist   = (int*)(ws + 6800000);      //    100,000  \  zeroed
    int*      cursor = (int*)(ws + 6900000);      //    100,000  /  region
    int*      row_ptr= (int*)(ws + 7000512);      //    100,001
    int*      part   = (int*)(ws + 7100513);      //        512
    uint2*    csr8   = (uint2*)(ws + 7101026);    //  2,200,000 floats (8B aligned)
    float*    bpart  = ws + 9301026;              //    524,288 (2048*256)
    float*    p2     = ws + 9825314;              //      4,096 (16*256)

    hipMemsetAsync(hist, 0, (size_t)200000 * sizeof(int), stream);

    k_gemmhist<<<1024, 256, 0, stream>>>(x, W, atts, attd, hB,
                                         (float2*)asrc, (float2*)adst, ei, hist);
    k_scan1   <<<NB, 256, 0, stream>>>(hist, part);
    k_scan3   <<<NB, 256, 0, stream>>>(hist, part, row_ptr);
    k_bucket  <<<(ET + 255) / 256, 256, 0, stream>>>(ei, asrc, adst, row_ptr,
                                                     cursor, csr8);
    k_agg     <<<AGG_BLOCKS, 256, 0, stream>>>(row_ptr, csr8, hB, bias,
                                               out, bpart);
    k_red     <<<16, 256, 0, stream>>>(bpart, p2);
    k_apply   <<<2048, 256, 0, stream>>>(p2, gamma, beta, out);
}

// Round 19
// 299.108 us; speedup vs baseline: 1.0391x; 1.0347x over previous
//
#include <hip/hip_runtime.h>

#define NN 100000
#define EE 1000000
#define ET (EE + NN)
#define HC 128
#define NB 391           // ceil(NN/256)
#define AGG_BLOCKS 2048  // persistent blocks for k_agg
#define NGRP (NN / 4)    // 25000 node groups of 4
#define NTILE 6250       // NN/16 row-tiles
#define GEMM_BLKS 768    // gemm blocks inside k_gemmhist (then 256 hist blocks)

typedef __attribute__((ext_vector_type(8))) short short8;
typedef __attribute__((ext_vector_type(4))) float f32x4;

// pack two floats to bf16x2 (RNE) in ONE instruction: a->low16, b->high16
__device__ __forceinline__ unsigned cvtpk(float a, float b) {
    unsigned r;
    asm("v_cvt_pk_bf16_f32 %0, %1, %2" : "=v"(r) : "v"(a), "v"(b));
    return r;
}

// ---- K1: fused  [blocks 0..767]: h = x@W via MFMA (+ attention dots)
//                 [blocks 768..1023]: degree histogram (independent, overlapped)
__global__ __launch_bounds__(256) void k_gemmhist(
    const float* __restrict__ x, const float* __restrict__ W,
    const float* __restrict__ atts, const float* __restrict__ attd,
    unsigned* __restrict__ hB, float2* __restrict__ asrc2, float2* __restrict__ adst2,
    const int* __restrict__ ei, int* __restrict__ hist)
{
    __shared__ uint4 wl[2048];   // 32 KB: B-fragments for all (ks, nt)

    if (blockIdx.x >= GEMM_BLKS) {
        // ---- histogram branch ----
        const int t0 = (blockIdx.x - GEMM_BLKS) * 256 + threadIdx.x;
        for (int t = t0; t < ET; t += 256 * 256) {
            int d = (t < EE) ? ei[EE + t] : (t - EE);
            atomicAdd(&hist[d], 1);
        }
        return;
    }

    // ---- gemm branch: pack W into B-fragment layout directly (L2-broadcast) ----
    for (int i = threadIdx.x; i < 2048; i += 256) {
        const int bid = i >> 6, l = i & 63;
        const int ks = bid >> 3, nt = bid & 7;
        const int n = nt * 16 + (l & 15);
        const int k0 = ks * 32 + (l >> 4) * 8;
        wl[i] = make_uint4(cvtpk(W[(k0 + 0) * HC + n], W[(k0 + 1) * HC + n]),
                           cvtpk(W[(k0 + 2) * HC + n], W[(k0 + 3) * HC + n]),
                           cvtpk(W[(k0 + 4) * HC + n], W[(k0 + 5) * HC + n]),
                           cvtpk(W[(k0 + 6) * HC + n], W[(k0 + 7) * HC + n]));
    }
    __syncthreads();

    const int wv = threadIdx.x >> 6, lane = threadIdx.x & 63;
    const int g = lane >> 4, c15 = lane & 15;

    float As[8], Ad[8];
    #pragma unroll
    for (int nt = 0; nt < 8; ++nt) {
        As[nt] = atts[nt * 16 + c15];
        Ad[nt] = attd[nt * 16 + c15];
    }

    for (int t = blockIdx.x * 4 + wv; t < NTILE; t += GEMM_BLKS * 4) {
        const int row0 = t * 16;
        union { unsigned u[4]; short8 v; } af[4];
        const float* xr = x + (size_t)(row0 + c15) * HC + g * 8;
        #pragma unroll
        for (int ks = 0; ks < 4; ++ks) {
            float4 lo = *(const float4*)(xr + ks * 32);
            float4 hi = *(const float4*)(xr + ks * 32 + 4);
            af[ks].u[0] = cvtpk(lo.x, lo.y);
            af[ks].u[1] = cvtpk(lo.z, lo.w);
            af[ks].u[2] = cvtpk(hi.x, hi.y);
            af[ks].u[3] = cvtpk(hi.z, hi.w);
        }
        f32x4 acc[8];
        #pragma unroll
        for (int nt = 0; nt < 8; ++nt) acc[nt] = (f32x4)(0.f);
        #pragma unroll
        for (int nt = 0; nt < 8; ++nt) {
            #pragma unroll
            for (int ks = 0; ks < 4; ++ks) {
                short8 bfr = *(const short8*)&wl[(ks * 8 + nt) * 64 + lane];
                acc[nt] = __builtin_amdgcn_mfma_f32_16x16x32_bf16(
                    af[ks].v, bfr, acc[nt], 0, 0, 0);
            }
        }
        #pragma unroll
        for (int r = 0; r < 4; ++r) {
            const int row = row0 + g * 4 + r;
            float ps = 0.f, pd = 0.f, qs = 0.f, qd = 0.f;
            #pragma unroll
            for (int nt = 0; nt < 4; ++nt) {
                float a = acc[nt][r], b = acc[nt + 4][r];
                hB[(size_t)row * 64 + nt * 16 + c15] = cvtpk(a, b);
                ps += a * As[nt];     qs += a * Ad[nt];
                pd += b * As[nt + 4]; qd += b * Ad[nt + 4];
            }
            for (int off = 8; off; off >>= 1) {
                ps += __shfl_xor(ps, off); pd += __shfl_xor(pd, off);
                qs += __shfl_xor(qs, off); qd += __shfl_xor(qd, off);
            }
            if (c15 == 0) {
                asrc2[row] = make_float2(ps, pd);
                adst2[row] = make_float2(qs, qd);
            }
        }
    }
}

__device__ __forceinline__ void edge_sd(const int* __restrict__ ei, int t, int& s, int& d) {
    if (t < EE) { s = ei[t]; d = ei[EE + t]; }
    else        { s = t - EE; d = t - EE; }           // self-loops appended
}

// ---- CSR scan: per-256-block sums ----
__global__ __launch_bounds__(256) void k_scan1(const int* __restrict__ hist,
                                               int* __restrict__ part)
{
    __shared__ int ls[256];
    int i = blockIdx.x * 256 + threadIdx.x;
    ls[threadIdx.x] = (i < NN) ? hist[i] : 0;
    __syncthreads();
    for (int off = 128; off; off >>= 1) {
        if (threadIdx.x < off) ls[threadIdx.x] += ls[threadIdx.x + off];
        __syncthreads();
    }
    if (!threadIdx.x) part[blockIdx.x] = ls[0];
}

// ---- scan3 (with fused scan-of-partials): row_ptr = exclusive scan of hist ----
__global__ __launch_bounds__(256) void k_scan3(const int* __restrict__ hist,
                                               const int* __restrict__ part,
                                               int* __restrict__ row_ptr)
{
    __shared__ int ls[256];
    __shared__ int bofs[NB];
    const int tid = threadIdx.x;
    if (tid < 64) {                      // wave 0: exclusive scan of 391 partials
        int carry = 0;
        for (int c = 0; c < NB; c += 64) {
            const int idx = c + tid;
            int v = (idx < NB) ? part[idx] : 0;
            const int orig = v;
            for (int o = 1; o < 64; o <<= 1) {
                int u = __shfl_up(v, o);
                if (tid >= o) v += u;
            }
            if (idx < NB) bofs[idx] = carry + v - orig;
            carry += __shfl(v, 63);
        }
    }
    int i = blockIdx.x * 256 + tid;
    int v = (i < NN) ? hist[i] : 0;
    ls[tid] = v;
    __syncthreads();
    for (int off = 1; off < 256; off <<= 1) {
        int t = (tid >= off) ? ls[tid - off] : 0;
        __syncthreads();
        ls[tid] += t;
        __syncthreads();
    }
    if (i < NN) row_ptr[i] = bofs[blockIdx.x] + ls[tid] - v;  // exclusive
    if (i == 0) row_ptr[NN] = ET;
}

// bucket edges by dst; ONE scattered 8B write per edge: {src, p as bf16x2}
__global__ __launch_bounds__(256) void k_bucket(
    const int* __restrict__ ei, const float* __restrict__ asrc,
    const float* __restrict__ adst, const int* __restrict__ row_ptr,
    int* __restrict__ cursor, uint2* __restrict__ csr8)
{
    int t = blockIdx.x * 256 + threadIdx.x;
    if (t >= ET) return;
    int s, d; edge_sd(ei, t, s, d);
    float2 av = *(const float2*)&asrc[s * 2];
    float2 dv = *(const float2*)&adst[d * 2];
    float e0 = av.x + dv.x; e0 = e0 > 0.f ? e0 : 0.2f * e0;
    float e1 = av.y + dv.y; e1 = e1 > 0.f ? e1 : 0.2f * e1;
    int pos = row_ptr[d] + atomicAdd(&cursor[d], 1);
    csr8[pos] = make_uint2((unsigned)s, cvtpk(__expf(e0), __expf(e1)));
}

// 8 dwordx2 gathers (= 16 edges, 2 edges/load) issued + drained in ONE asm
// block; nothing (spill/copy/compiler-wait) can land between issue and drain.
__device__ __forceinline__ void gather8x2(const unsigned* base, const unsigned* off,
                                          unsigned long long* w) {
    asm volatile(
        "global_load_dwordx2 %0, %8,  %16\n\t"
        "global_load_dwordx2 %1, %9,  %16\n\t"
        "global_load_dwordx2 %2, %10, %16\n\t"
        "global_load_dwordx2 %3, %11, %16\n\t"
        "global_load_dwordx2 %4, %12, %16\n\t"
        "global_load_dwordx2 %5, %13, %16\n\t"
        "global_load_dwordx2 %6, %14, %16\n\t"
        "global_load_dwordx2 %7, %15, %16\n\t"
        "s_waitcnt vmcnt(0)"
        : "=&v"(w[0]), "=&v"(w[1]), "=&v"(w[2]), "=&v"(w[3]),
          "=&v"(w[4]), "=&v"(w[5]), "=&v"(w[6]), "=&v"(w[7])
        : "v"(off[0]), "v"(off[1]), "v"(off[2]), "v"(off[3]),
          "v"(off[4]), "v"(off[5]), "v"(off[6]), "v"(off[7]),
          "s"(base)
        : "memory");
}

// ---- K-agg: 8B csr entries, 16 edges in flight ----
// lane = half*32 + m: half 0 even-slot edges, half 1 odd-slot.
// lane covers channels {2m, 2m+1, 2m+64, 2m+65} (dwords 2m, 2m+1 of hB row).
__global__ __launch_bounds__(256) void k_agg(
    const int* __restrict__ row_ptr, const uint2* __restrict__ csr8,
    const unsigned* __restrict__ hB, const float* __restrict__ bias,
    float* __restrict__ out, float* __restrict__ bpart)
{
    __shared__ float lsum[HC], lsq[HC];
    __shared__ int    lidx[4][64];
    __shared__ float2 lp[4][64];
    const int tid = threadIdx.x;
    if (tid < HC) { lsum[tid] = 0.f; lsq[tid] = 0.f; }
    __syncthreads();

    const int wv = tid >> 6, lane = tid & 63;
    const int half = lane >> 5, m = lane & 31;
    const float bA0 = bias[2*m],      bB0 = bias[2*m + 1];
    const float bA1 = bias[2*m + 64], bB1 = bias[2*m + 65];

    for (int g = blockIdx.x; g < NGRP; g += AGG_BLOCKS) {
        const int node = g * 4 + wv;
        const int beg = row_ptr[node], end = row_ptr[node + 1];  // end > beg

        float s0 = 0.f, s1 = 0.f;
        float a0 = 0.f, a1 = 0.f, b0 = 0.f, b1 = 0.f;  // ch 2m, 2m+64, 2m+1, 2m+65

        for (int base = beg; base < end; base += 64) {
            const int cnt = min(64, end - base);   // >= 1
            if (lane < cnt) {
                uint2 e = csr8[base + lane];       // one coalesced 8B load
                float2 pv = make_float2(__uint_as_float(e.y << 16),
                                        __uint_as_float(e.y & 0xffff0000u));
                lidx[wv][lane] = (int)e.x;
                lp[wv][lane] = pv;
                s0 += pv.x; s1 += pv.y;
            }
            for (int j0 = 0; j0 < cnt; j0 += 16) {
                unsigned off[8]; unsigned long long w[8];
                float px[8], py[8];
                #pragma unroll
                for (int u = 0; u < 8; ++u) {
                    int j  = j0 + 2 * u + half;
                    int jc = j < cnt ? j : cnt - 1;     // clamp (wave-uniform)
                    int s  = lidx[wv][jc];
                    float2 pv = lp[wv][jc];
                    px[u] = j < cnt ? pv.x : 0.f;       // zero pad weight
                    py[u] = j < cnt ? pv.y : 0.f;
                    off[u] = ((unsigned)s * 64u + (unsigned)m * 2u) * 4u;
                }
                gather8x2(hB, off, w);
                #pragma unroll
                for (int u = 0; u < 8; ++u) {
                    unsigned wlo = (unsigned)w[u];           // dword 2m
                    unsigned whi = (unsigned)(w[u] >> 32);   // dword 2m+1
                    a0 = fmaf(px[u], __uint_as_float(wlo << 16),          a0);
                    a1 = fmaf(py[u], __uint_as_float(wlo & 0xffff0000u),  a1);
                    b0 = fmaf(px[u], __uint_as_float(whi << 16),          b0);
                    b1 = fmaf(py[u], __uint_as_float(whi & 0xffff0000u),  b1);
                }
            }
        }

        // combine edge-halves, then full reduce of p-sums
        a0 += __shfl_xor(a0, 32); a1 += __shfl_xor(a1, 32);
        b0 += __shfl_xor(b0, 32); b1 += __shfl_xor(b1, 32);
        for (int o = 32; o; o >>= 1) {
            s0 += __shfl_xor(s0, o);
            s1 += __shfl_xor(s1, o);
        }
        const float i0 = 1.f / s0, i1 = 1.f / s1;

        if (half == 0) {
            float vA0 = a0 * i0 + bA0; vA0 = vA0 > 0.f ? vA0 : 0.f;  // ch 2m
            float vB0 = b0 * i0 + bB0; vB0 = vB0 > 0.f ? vB0 : 0.f;  // ch 2m+1
            float vA1 = a1 * i1 + bA1; vA1 = vA1 > 0.f ? vA1 : 0.f;  // ch 2m+64
            float vB1 = b1 * i1 + bB1; vB1 = vB1 > 0.f ? vB1 : 0.f;  // ch 2m+65
            *(float2*)&out[(size_t)node * HC + 2*m]      = make_float2(vA0, vB0);
            *(float2*)&out[(size_t)node * HC + 64 + 2*m] = make_float2(vA1, vB1);
            atomicAdd(&lsum[2*m],      vA0); atomicAdd(&lsq[2*m],      vA0 * vA0);
            atomicAdd(&lsum[2*m + 1],  vB0); atomicAdd(&lsq[2*m + 1],  vB0 * vB0);
            atomicAdd(&lsum[2*m + 64], vA1); atomicAdd(&lsq[2*m + 64], vA1 * vA1);
            atomicAdd(&lsum[2*m + 65], vB1); atomicAdd(&lsq[2*m + 65], vB1 * vB1);
        }
    }

    __syncthreads();
    bpart[(size_t)blockIdx.x * 256 + tid] = tid < HC ? lsum[tid] : lsq[tid - HC];
}

// ---- reduce bpart[2048][256] -> p2[16][256] (atomic-free) ----
__global__ __launch_bounds__(256) void k_red(const float* __restrict__ bpart,
                                             float* __restrict__ p2)
{
    const int tid = threadIdx.x;
    float acc = 0.f;
    const int r0 = blockIdx.x * (AGG_BLOCKS / 16);
    #pragma unroll 4
    for (int r = 0; r < AGG_BLOCKS / 16; ++r)
        acc += bpart[(size_t)(r0 + r) * 256 + tid];
    p2[blockIdx.x * 256 + tid] = acc;
}

// ---- affine apply (BN params derived in-block from p2) ----
__global__ __launch_bounds__(256) void k_apply(
    const float* __restrict__ p2, const float* __restrict__ gamma,
    const float* __restrict__ beta, float* __restrict__ out)
{
    __shared__ float scsh[256];
    const int tid = threadIdx.x;
    if (tid < HC) {
        float sum = 0.f, sq = 0.f;
        #pragma unroll
        for (int i = 0; i < 16; ++i) {
            sum += p2[i * 256 + tid];
            sq  += p2[i * 256 + tid + 128];
        }
        float mean = sum * (1.f / NN);
        float var  = sq * (1.f / NN) - mean * mean;
        float sc   = gamma[tid] * rsqrtf(var + 1e-5f);
        scsh[tid]       = sc;
        scsh[128 + tid] = beta[tid] - mean * sc;
    }
    __syncthreads();
    for (size_t i = (size_t)blockIdx.x * 256 + tid; i < (size_t)NN * HC / 4;
         i += (size_t)gridDim.x * 256) {
        float4 v = ((float4*)out)[i];
        int c = (int)((i * 4) & (HC - 1));
        v.x = v.x * scsh[c]     + scsh[128 + c];
        v.y = v.y * scsh[c + 1] + scsh[128 + c + 1];
        v.z = v.z * scsh[c + 2] + scsh[128 + c + 2];
        v.w = v.w * scsh[c + 3] + scsh[128 + c + 3];
        ((float4*)out)[i] = v;
    }
}

extern "C" void kernel_launch(void* const* d_in, const int* in_sizes, int n_in,
                              void* d_out, int out_size, void* d_ws, size_t ws_size,
                              hipStream_t stream) {
    const float* x     = (const float*)d_in[0];
    const int*   ei    = (const int*)  d_in[1];
    const float* W     = (const float*)d_in[2];
    const float* atts  = (const float*)d_in[3];
    const float* attd  = (const float*)d_in[4];
    const float* bias  = (const float*)d_in[5];
    const float* gamma = (const float*)d_in[6];
    const float* beta  = (const float*)d_in[7];
    float* out = (float*)d_out;
    float* ws  = (float*)d_ws;

    // ws layout (float-sized slots), ~40 MB total
    unsigned* hB     = (unsigned*)ws;             //  6,400,000
    float*    asrc   = ws + 6400000;              //    200,000
    float*    adst   = ws + 6600000;              //    200,000
    int*      hist   = (int*)(ws + 6800000);      //    100,000  \  zeroed
    int*      cursor = (int*)(ws + 6900000);      //    100,000  /  region
    int*      row_ptr= (int*)(ws + 7000512);      //    100,001
    int*      part   = (int*)(ws + 7100513);      //        512
    uint2*    csr8   = (uint2*)(ws + 7101026);    //  2,200,000 floats (8B aligned)
    float*    bpart  = ws + 9301026;              //    524,288 (2048*256)
    float*    p2     = ws + 9825314;              //      4,096 (16*256)

    hipMemsetAsync(hist, 0, (size_t)200000 * sizeof(int), stream);

    k_gemmhist<<<1024, 256, 0, stream>>>(x, W, atts, attd, hB,
                                         (float2*)asrc, (float2*)adst, ei, hist);
    k_scan1   <<<NB, 256, 0, stream>>>(hist, part);
    k_scan3   <<<NB, 256, 0, stream>>>(hist, part, row_ptr);
    k_bucket  <<<(ET + 255) / 256, 256, 0, stream>>>(ei, asrc, adst, row_ptr,
                                                     cursor, csr8);
    k_agg     <<<AGG_BLOCKS, 256, 0, stream>>>(row_ptr, csr8, hB, bias,
                                               out, bpart);
    k_red     <<<16, 256, 0, stream>>>(bpart, p2);
    k_apply   <<<2048, 256, 0, stream>>>(p2, gamma, beta, out);
}